// Round 2
// baseline (901.896 us; speedup 1.0000x reference)
//
#include <hip/hip_runtime.h>

// Potts energy kernel for MI355X.
// B=2, N=4096, K=48, Q=20.
// Outputs (flat concat): U (B,) then U_i (B,N,Q), fp32.
//
// R5: structural experiment. R3 (interleaved) and R4 (batch-issued loads) both
// pinned at ~385us (~1.65 TB/s) for the 629 MB J stream -> the limiter is not
// wave-level MLP (300KB/CU was in flight vs ~9KB needed). Suspect: the macro
// shape (single-shot 5-wave blocks, barrier-sandwiched 75KB bursts, lockstep
// cohorts). This version is copy-benchmark-shaped: 24576 one-wave blocks
// (node x 16-neighbor group), 25 exact float4/lane, fully branchless stream
// (unconditional ds_add with 0-masked value, no exec-mask ops, no barrier in
// the stream), partials merged via ~20 global fp32 atomics per block into
// U_i pre-initialized to h. node_c is folded algebraically into the reduce:
// U contribution per node = 0.5*(U_i[s] + h[s]).

constexpr int Bc = 2;
constexpr int Nc = 4096;
constexpr int Kc = 48;
constexpr int Qc = 20;
constexpr int KG   = 16;                    // neighbors per block
constexpr int NKG  = Kc / KG;               // 3 groups per node
constexpr int GRP_F4 = KG * Qc * Qc / 4;    // 1600 float4 per group
constexpr int TPB_A  = 64;                  // one wave
constexpr int NITER  = GRP_F4 / TPB_A;      // 25 exact

// U_i[i] = h[i]  (163840 floats = 40960 float4)
__global__ __launch_bounds__(256) void potts_init_kernel(
    const float* __restrict__ h, float* __restrict__ U_i)
{
    const int i = blockIdx.x * 256 + threadIdx.x;   // grid sized exactly
    ((float4*)U_i)[i] = ((const float4*)h)[i];
}

__global__ __launch_bounds__(TPB_A) void potts_stream_kernel(
    const int*   __restrict__ S,
    const float* __restrict__ J,
    const int*   __restrict__ edge_idx,
    float*       __restrict__ U_i)          // (B*N*Q), pre-init to h
{
    const int unit = blockIdx.x;            // 0 .. B*N*NKG-1
    const int node = unit / NKG;            // 0 .. B*N-1
    const int kg   = unit - node * NKG;     // 0 .. 2
    const int b    = node >> 12;
    const int lane = threadIdx.x;

    __shared__ float Jl[Qc];
    __shared__ int   sj[KG];

    if (lane < Qc) Jl[lane] = 0.0f;
    if (lane < KG) {
        int e = edge_idx[node * Kc + kg * KG + lane];
        sj[lane] = S[b * Nc + e];
    }
    __syncthreads();

    // Branchless coalesced stream over this unit's 16 k-rows (6400 floats).
    // No exec-mask ops in the loop -> compiler is free to pipeline loads.
    const float4* Jf4 = (const float4*)J + (size_t)node * (Kc * Qc * Qc / 4)
                                         + (size_t)kg * GRP_F4;
    #pragma unroll
    for (int i = 0; i < NITER; ++i) {
        const int m = i * TPB_A + lane;     // 0 .. 1599
        float4 v = Jf4[m];
        int k  = m / 100;                   // 100 float4 per k-row
        int r  = m - k * 100;
        int q  = r / 5;                     // 5 float4 per q-row
        int s0 = (r - q * 5) << 2;
        int d  = sj[k] - s0;                // element index within this f4
        float val = (d == 0) ? v.x : (d == 1) ? v.y : (d == 2) ? v.z : v.w;
        val = ((unsigned)d < 4u) ? val : 0.0f;
        atomicAdd(&Jl[q], val);             // unconditional ds_add_f32
    }
    __syncthreads();

    if (lane < Qc) atomicAdd(&U_i[node * Qc + lane], Jl[lane]);
}

// U[b] = sum_n 0.5*(U_i[b,n,S[b,n]] + h[b,n,S[b,n]])
__global__ __launch_bounds__(256) void potts_reduce_kernel(
    const int*   __restrict__ S,
    const float* __restrict__ h,
    const float* __restrict__ U_i,
    float*       __restrict__ U)
{
    const int b   = blockIdx.x;
    const int tid = threadIdx.x;
    float s = 0.0f;
    for (int n = tid; n < Nc; n += 256) {
        int st  = S[b * Nc + n];
        int idx = (b * Nc + n) * Qc + st;
        s += 0.5f * (U_i[idx] + h[idx]);
    }
    #pragma unroll
    for (int off = 32; off > 0; off >>= 1) s += __shfl_down(s, off, 64);
    __shared__ float ws[4];
    if ((tid & 63) == 0) ws[tid >> 6] = s;
    __syncthreads();
    if (tid == 0) U[b] = ws[0] + ws[1] + ws[2] + ws[3];
}

extern "C" void kernel_launch(void* const* d_in, const int* in_sizes, int n_in,
                              void* d_out, int out_size, void* d_ws, size_t ws_size,
                              hipStream_t stream) {
    const int*   S        = (const int*)  d_in[0];
    const float* h        = (const float*)d_in[1];
    const float* J        = (const float*)d_in[2];
    const int*   edge_idx = (const int*)  d_in[3];

    float* out = (float*)d_out;
    float* U   = out;        // 2 floats
    float* U_i = out + Bc;   // B*N*Q floats

    potts_init_kernel<<<Bc * Nc * Qc / 4 / 256, 256, 0, stream>>>(h, U_i);
    potts_stream_kernel<<<Bc * Nc * NKG, TPB_A, 0, stream>>>(S, J, edge_idx, U_i);
    potts_reduce_kernel<<<Bc, 256, 0, stream>>>(S, h, U_i, U);
}

// Round 3
// 796.105 us; speedup vs baseline: 1.1329x; 1.1329x over previous
//
#include <hip/hip_runtime.h>

// Potts energy kernel for MI355X.
// B=2, N=4096, K=48, Q=20.
// Outputs (flat concat): U (B,) then U_i (B,N,Q), fp32.
//
// R6: stop streaming all of J. Only column S_j[k] of each 20x20 block is
// needed: 20 floats at stride 80 B per (node,k). Full-stream variants (R3
// interleaved, R4 batch-issued, R5 copy-shaped) all pinned at ~389 us
// (~1.6 TB/s) regardless of schedule, so this version cuts the request
// stream itself: lane = k (48 of 64 active), 20 scattered dword loads per
// lane from ONE base register + immediate offsets (q*80 bytes), no selects,
// no atomics. 64B-sector floor: 20 distinct sectors per (node,k) = 1280 B
// fetched vs 1600 B full block -> ~503 MB total vs 629 MB, and 5x fewer
// load instrs / register bytes / VALU.
// Accumulate via padded LDS transpose T[48][21] (<=2-way banks, free),
// then 20 lanes produce U_i and the s_i lane writes the node scalar.
// Single-wave blocks: __syncthreads() is just a waitcnt, no real barrier.

constexpr int Bc = 2;
constexpr int Nc = 4096;
constexpr int Kc = 48;
constexpr int Qc = 20;
constexpr int NODE_FLOATS = Kc * Qc * Qc;   // 19200

__global__ __launch_bounds__(64) void potts_gather_kernel(
    const int*   __restrict__ S,
    const float* __restrict__ h,
    const float* __restrict__ J,
    const int*   __restrict__ edge_idx,
    float*       __restrict__ U_i_out,   // (B*N*Q)
    float*       __restrict__ node_c)    // (B*N)
{
    const int node = blockIdx.x;          // 0 .. B*N-1
    const int b    = node >> 12;
    const int l    = threadIdx.x;         // 0 .. 63

    __shared__ float T[Kc][Qc + 1];       // +1 pad: <=2-way bank aliasing

    const int s_i = S[node];              // uniform scalar load

    if (l < Kc) {
        const int e  = edge_idx[node * Kc + l];   // coalesced 192 B
        const int sl = S[b * Nc + e];             // 16 KB table, L1
        // Base points at column sl of this (node,k) 20x20 block.
        const float* Jp = J + (size_t)node * NODE_FLOATS + l * (Qc * Qc) + sl;
        float v[Qc];
        #pragma unroll
        for (int q = 0; q < Qc; ++q) v[q] = Jp[q * Qc];   // offset:q*80, batched
        #pragma unroll
        for (int q = 0; q < Qc; ++q) T[l][q] = v[q];
    }
    __syncthreads();   // single wave: compiles to waitcnt only

    if (l < Qc) {
        float ji = 0.0f;
        #pragma unroll
        for (int k = 0; k < Kc; ++k) ji += T[k][l];
        const float ui = h[node * Qc + l] + ji;
        U_i_out[node * Qc + l] = ui;
        if (l == s_i) {
            // U contribution: (h[s]+J_i[s]) - 0.5*J_i[s] = ui - 0.5*ji
            node_c[node] = ui - 0.5f * ji;
        }
    }
}

__global__ __launch_bounds__(256) void potts_reduce_kernel(
    const float* __restrict__ node_c, float* __restrict__ U)
{
    const int b   = blockIdx.x;
    const int tid = threadIdx.x;
    float s = 0.0f;
    for (int i = tid; i < Nc; i += 256) s += node_c[b * Nc + i];
    #pragma unroll
    for (int off = 32; off > 0; off >>= 1) s += __shfl_down(s, off, 64);
    __shared__ float ws[4];
    if ((tid & 63) == 0) ws[tid >> 6] = s;
    __syncthreads();
    if (tid == 0) U[b] = ws[0] + ws[1] + ws[2] + ws[3];
}

extern "C" void kernel_launch(void* const* d_in, const int* in_sizes, int n_in,
                              void* d_out, int out_size, void* d_ws, size_t ws_size,
                              hipStream_t stream) {
    const int*   S        = (const int*)  d_in[0];
    const float* h        = (const float*)d_in[1];
    const float* J        = (const float*)d_in[2];
    const int*   edge_idx = (const int*)  d_in[3];

    float* out    = (float*)d_out;
    float* U      = out;        // 2 floats
    float* U_i    = out + Bc;   // B*N*Q floats
    float* node_c = (float*)d_ws;

    potts_gather_kernel<<<Bc * Nc, 64, 0, stream>>>(S, h, J, edge_idx, U_i, node_c);
    potts_reduce_kernel<<<Bc, 256, 0, stream>>>(node_c, U);
}